// Round 1
// baseline (240.221 us; speedup 1.0000x reference)
//
#include <hip/hip_runtime.h>
#include <math.h>

#define NPIX 65536
#define NB   4
#define NK   6
#define TK   8
#define NBUK 48   // NK*TK
#define NCH  256

// ---------------- init: zero the atomic targets ----------------
__global__ __launch_bounds__(64) void k_init(unsigned* m_arr, unsigned* Mbits) {
  int t = threadIdx.x;
  if (t < NB * NK) { m_arr[t] = 0u; Mbits[t] = 0u; }
}

// ---------------- A1: cert, argmax, per-class count m and max M ----------------
__global__ __launch_bounds__(256) void k_cert(const float* __restrict__ preds,
    float* __restrict__ cert, unsigned char* __restrict__ argm,
    unsigned* __restrict__ m_arr, unsigned* __restrict__ Mbits) {
  __shared__ unsigned s_cnt[NK], s_max[NK];
  int tid = threadIdx.x;
  if (tid < NK) { s_cnt[tid] = 0u; s_max[tid] = 0u; }
  __syncthreads();
  int i = blockIdx.x * 256 + tid;           // 0..65535, 4 pixels each
  int n4 = i << 2;
  int b = n4 >> 16;                          // NPIX = 2^16
  int n = n4 & (NPIX - 1);
  const float* pb = preds + (size_t)b * NK * NPIX + n;
  float4 pv[NK];
  #pragma unroll
  for (int k = 0; k < NK; ++k) pv[k] = *(const float4*)(pb + (size_t)k * NPIX);
  float cv[4]; unsigned av = 0;
  #pragma unroll
  for (int j = 0; j < 4; ++j) {
    float m1 = -INFINITY, m2 = -INFINITY; int arg = 0;
    #pragma unroll
    for (int k = 0; k < NK; ++k) {
      float v = (j == 0) ? pv[k].x : (j == 1) ? pv[k].y : (j == 2) ? pv[k].z : pv[k].w;
      if (v > m1) { m2 = m1; m1 = v; arg = k; }
      else if (v > m2) m2 = v;
    }
    float c = m1 - m2;                       // >= 0 always
    cv[j] = c;
    av |= ((unsigned)arg) << (8 * j);
    atomicAdd(&s_cnt[arg], 1u);
    atomicMax(&s_max[arg], __float_as_uint(c));
  }
  *(float4*)(cert + (size_t)b * NPIX + n) = make_float4(cv[0], cv[1], cv[2], cv[3]);
  *(unsigned*)(argm + (size_t)b * NPIX + n) = av;
  __syncthreads();
  if (tid < NK) {
    if (s_cnt[tid]) atomicAdd(&m_arr[b * NK + tid], s_cnt[tid]);
    atomicMax(&Mbits[b * NK + tid], s_max[tid]);
  }
}

// ---------------- A2: per-(b,c,t) exact k-th largest via radix select ----------------
__global__ __launch_bounds__(256) void k_thresh(const float* __restrict__ cert,
    const unsigned char* __restrict__ argm, const unsigned* __restrict__ m_arr,
    float* __restrict__ thr) {
  int g = blockIdx.x;                        // 0..191
  int b = g / (NK * TK);
  int rem = g % (NK * TK);
  int c = rem / TK;
  int t = rem % TK;                          // 0-based; ref t = t+1
  int tid = threadIdx.x;
  unsigned m = m_arr[b * NK + c];
  if (m == 0) { if (tid == 0) thr[g] = 0.f; return; }
  unsigned long long ks = ((unsigned long long)m * (unsigned)(t + 1)) / TK;
  unsigned rank = (ks == 0) ? 1u : (unsigned)ks;   // rank-th largest (1-based), = clip(ks-1,0,..)+1
  __shared__ unsigned hist[256];
  __shared__ unsigned s_bin, s_rank;
  const float* cb = cert + (size_t)b * NPIX;
  const unsigned char* ab = argm + (size_t)b * NPIX;
  unsigned prefix = 0;
  for (int pass = 0; pass < 4; ++pass) {
    int shift = 24 - 8 * pass;
    hist[tid] = 0u;
    __syncthreads();
    for (int n0 = tid * 4; n0 < NPIX; n0 += 1024) {
      float4 cv = *(const float4*)(cb + n0);
      unsigned av = *(const unsigned*)(ab + n0);
      #pragma unroll
      for (int j = 0; j < 4; ++j) {
        if (((av >> (8 * j)) & 255u) == (unsigned)c) {
          unsigned u = __float_as_uint((j == 0) ? cv.x : (j == 1) ? cv.y : (j == 2) ? cv.z : cv.w);
          if (pass == 0 || (u >> (shift + 8)) == prefix)
            atomicAdd(&hist[(u >> shift) & 255u], 1u);
        }
      }
    }
    __syncthreads();
    if (tid == 0) {
      unsigned cum = 0, sel = 0, rn = rank;
      for (int bin = 255; bin >= 0; --bin) {
        unsigned h = hist[bin];
        cum += h;
        if (cum >= rank) { sel = (unsigned)bin; rn = rank - (cum - h); break; }
      }
      s_bin = sel; s_rank = rn;
    }
    __syncthreads();
    prefix = (prefix << 8) | s_bin;
    rank = s_rank;
    __syncthreads();
  }
  if (tid == 0) thr[g] = __uint_as_float(prefix);
}

// ---------------- A3: per-pixel weight e and incremental bucket id ----------------
__global__ __launch_bounds__(256) void k_bucket(const float* __restrict__ cert,
    const unsigned char* __restrict__ argm, const unsigned* __restrict__ Mbits,
    const float* __restrict__ thr, float* __restrict__ e_out,
    unsigned char* __restrict__ bid_out) {
  __shared__ float s_thr[NB * NBUK];
  __shared__ float s_M[NB * NK];
  int tid = threadIdx.x;
  if (tid < NB * NBUK) s_thr[tid] = thr[tid];
  if (tid < NB * NK)  s_M[tid] = __uint_as_float(Mbits[tid]);
  __syncthreads();
  int i = blockIdx.x * 256 + tid;
  int n4 = i << 2;
  int b = n4 >> 16;
  int n = n4 & (NPIX - 1);
  float4 cv = *(const float4*)(cert + (size_t)b * NPIX + n);
  unsigned av = *(const unsigned*)(argm + (size_t)b * NPIX + n);
  float ev[4]; unsigned bidp = 0;
  #pragma unroll
  for (int j = 0; j < 4; ++j) {
    int c = (av >> (8 * j)) & 255;
    float ce = (j == 0) ? cv.x : (j == 1) ? cv.y : (j == 2) ? cv.z : cv.w;
    float e = expf(ce - s_M[b * NK + c]);
    const float* tc = &s_thr[(b * NK + c) * TK];
    int tmin = TK - 1;                          // guaranteed ce >= thr[TK-1]
    #pragma unroll
    for (int tt = TK - 2; tt >= 0; --tt) if (ce >= tc[tt]) tmin = tt;
    ev[j] = e;
    bidp |= ((unsigned)(c * TK + tmin)) << (8 * j);
  }
  *(float4*)(e_out + (size_t)b * NPIX + n) = make_float4(ev[0], ev[1], ev[2], ev[3]);
  *(unsigned*)(bid_out + (size_t)b * NPIX + n) = bidp;
}

// ---------------- B: single pass over x, lane-owned LDS bucket accumulators ----------------
// grid = NB*(NCH+1); chz==NCH is the "z-plane" (x==1) giving deterministic Z sums.
__global__ __launch_bounds__(256) void k_accum(const float* __restrict__ x,
    const float* __restrict__ e_in, const unsigned char* __restrict__ bid_in,
    float* __restrict__ psum, float* __restrict__ zbuf) {
  __shared__ float acc[4 * NBUK * 64];        // [wave][bucket][lane], stride 64 -> bank = lane%32 (free)
  __shared__ float wpart[4 * NBUK];
  int tid = threadIdx.x;
  int w = tid >> 6, lane = tid & 63;
  float* mycol = acc + (size_t)w * NBUK * 64 + lane;
  #pragma unroll
  for (int k = 0; k < NBUK; ++k) mycol[k * 64] = 0.f;
  __syncthreads();
  int blk = blockIdx.x;
  int b = blk / (NCH + 1);
  int chz = blk % (NCH + 1);
  bool isz = (chz == NCH);
  const float* ep = e_in + (size_t)b * NPIX;
  const unsigned* bp = (const unsigned*)(bid_in + (size_t)b * NPIX);
  const float* xp = x + ((size_t)b * NCH + chz) * NPIX;
  for (int it = 0; it < NPIX / 1024; ++it) {
    int off = it * 1024 + tid * 4;
    float4 evv = *(const float4*)(ep + off);
    unsigned bv = bp[off >> 2];
    float4 xv = make_float4(1.f, 1.f, 1.f, 1.f);
    if (!isz) xv = *(const float4*)(xp + off);
    { int bk = bv & 255u;         mycol[bk * 64] += xv.x * evv.x; }
    { int bk = (bv >> 8) & 255u;  mycol[bk * 64] += xv.y * evv.y; }
    { int bk = (bv >> 16) & 255u; mycol[bk * 64] += xv.z * evv.z; }
    { int bk = (bv >> 24) & 255u; mycol[bk * 64] += xv.w * evv.w; }
  }
  __syncthreads();
  for (int k = 0; k < NBUK; ++k) {
    float v = mycol[k * 64];                  // conflict-free (2 lanes/bank)
    #pragma unroll
    for (int d = 1; d < 64; d <<= 1) v += __shfl_xor(v, d, 64);
    if (lane == 0) wpart[w * NBUK + k] = v;
  }
  __syncthreads();
  if (tid < NBUK) {
    float s = wpart[tid] + wpart[NBUK + tid] + wpart[2 * NBUK + tid] + wpart[3 * NBUK + tid];
    if (!isz) psum[((size_t)b * NCH + chz) * NBUK + tid] = s;
    else      zbuf[(size_t)b * NBUK + tid] = s;
  }
}

// ---------------- F: prefix over t, branch on m, write fs + fg ----------------
__global__ __launch_bounds__(256) void k_final(const float* __restrict__ psum,
    const float* __restrict__ zbuf, const unsigned* __restrict__ m_arr,
    float* __restrict__ out) {
  int i = blockIdx.x * 256 + threadIdx.x;     // (b, ch)
  if (i >= NB * NCH) return;
  int b = i >> 8;
  const float* ps = psum + (size_t)i * NBUK;
  const float* zb = zbuf + (size_t)b * NBUK;
  float* fs = out + (size_t)i * NBUK;
  float* fg = out + (size_t)NB * NCH * NBUK + (size_t)i * NK;
  float t5[TK];
  #pragma unroll
  for (int c = 0; c < NK; ++c) {
    unsigned m = m_arr[b * NK + c];
    float P = 0.f, Z = 0.f;
    float vals[TK];
    #pragma unroll
    for (int t = 0; t < TK; ++t) {
      P += ps[c * TK + t];
      Z += zb[c * TK + t];
      vals[t] = P / Z;
    }
    float tot = vals[TK - 1];
    #pragma unroll
    for (int t = 0; t < TK; ++t) {
      float v = (m == 0u) ? 0.f : ((m < (unsigned)TK) ? tot : vals[t]);
      fs[c * TK + t] = v;
      if (c == NK - 1) t5[t] = v;
    }
  }
  // fg[v] = fs flat index 42+v  ->  class 5, t index 2+v
  #pragma unroll
  for (int v = 0; v < NK; ++v) fg[v] = t5[2 + v];
}

extern "C" void kernel_launch(void* const* d_in, const int* in_sizes, int n_in,
                              void* d_out, int out_size, void* d_ws, size_t ws_size,
                              hipStream_t stream) {
  const float* x     = (const float*)d_in[0];   // [4,256,256,256]
  const float* preds = (const float*)d_in[1];   // [4,6,256,256]
  float* out = (float*)d_out;
  char* ws = (char*)d_ws;
  float*         cert  = (float*)(ws);                       // 1 MiB
  float*         e     = (float*)(ws + 0x100000);            // 1 MiB
  unsigned char* argm  = (unsigned char*)(ws + 0x200000);    // 256 KiB
  unsigned char* bid   = (unsigned char*)(ws + 0x240000);    // 256 KiB
  unsigned*      m_arr = (unsigned*)(ws + 0x280000);         // 24 u32
  unsigned*      Mbits = (unsigned*)(ws + 0x280100);         // 24 u32
  float*         thr   = (float*)(ws + 0x280200);            // 192 f32
  float*         psum  = (float*)(ws + 0x280600);            // 192 KiB
  float*         zbuf  = (float*)(ws + 0x280600 + 196608);   // 192 f32

  k_init  <<<1, 64, 0, stream>>>(m_arr, Mbits);
  k_cert  <<<256, 256, 0, stream>>>(preds, cert, argm, m_arr, Mbits);
  k_thresh<<<NB * NK * TK, 256, 0, stream>>>(cert, argm, m_arr, thr);
  k_bucket<<<256, 256, 0, stream>>>(cert, argm, Mbits, thr, e, bid);
  k_accum <<<NB * (NCH + 1), 256, 0, stream>>>(x, e, bid, psum, zbuf);
  k_final <<<4, 256, 0, stream>>>(psum, zbuf, m_arr, out);
}